// Round 1
// baseline (670.249 us; speedup 1.0000x reference)
//
#include <hip/hip_runtime.h>
#include <math.h>

#define NEG 0.2f

typedef __bf16 bf16x8 __attribute__((ext_vector_type(8)));
typedef float  f32x4  __attribute__((ext_vector_type(4)));

// ---------------------------------------------------------------------------
// W1 pre-swizzle: W1[512,64] f32 -> W1b bf16 in MFMA B-fragment order.
// Slot i = (ch*4+lk)*64 + n holds 8 bf16: W1[ch*32+lk*8+j][n], j=0..7.
// ---------------------------------------------------------------------------
__global__ void w1prep_k(const float* __restrict__ W1, __bf16* __restrict__ W1b)
{
    int i = blockIdx.x * 256 + threadIdx.x;   // 0..4095
    int n = i & 63;
    int k0 = (i >> 6) * 8;                    // (ch*4+lk)*8 == ch*32+lk*8
#pragma unroll
    for (int j = 0; j < 8; ++j)
        W1b[(size_t)i * 8 + j] = (__bf16)W1[(size_t)(k0 + j) * 64 + n];
}

// ---------------------------------------------------------------------------
// K1: h1[N,64] = x[N,512] @ W1[512,64] via bf16 MFMA (16x16x32), PLUS fused
// per-(node,head) attention dots (as1/ad1) computed from the accumulator
// registers (saves the attn1_k re-read of h1).
// C/D: col = lane&15, row = (lane>>4)*4 + reg (verified m89). For the dots,
// head = col>>3; reduce c=0..7 with shfl_xor 1/2/4 inside each lm&7 group.
// ---------------------------------------------------------------------------
__global__ __launch_bounds__(256, 4) void gemm1a_k(const float* __restrict__ x,
                                                   const __bf16* __restrict__ W1b,
                                                   const float* __restrict__ asrc,
                                                   const float* __restrict__ adst,
                                                   float* __restrict__ h1,
                                                   float* __restrict__ as1,
                                                   float* __restrict__ ad1, int Nn)
{
    int t = threadIdx.x;
    int wave = t >> 6, lane = t & 63;
    int lm = lane & 15, lk = lane >> 4;
    int rowa = blockIdx.x * 64 + wave * 16 + lm;          // A: m = lane&15
    const float* xrow = x + (size_t)(rowa < Nn ? rowa : 0) * 512;
    f32x4 acc[4] = {};
#pragma unroll
    for (int ch = 0; ch < 16; ++ch) {
        float4 a0 = *(const float4*)(xrow + ch * 32 + lk * 8);
        float4 a1 = *(const float4*)(xrow + ch * 32 + lk * 8 + 4);
        bf16x8 af;
        af[0] = (__bf16)a0.x; af[1] = (__bf16)a0.y;
        af[2] = (__bf16)a0.z; af[3] = (__bf16)a0.w;
        af[4] = (__bf16)a1.x; af[5] = (__bf16)a1.y;
        af[6] = (__bf16)a1.z; af[7] = (__bf16)a1.w;
#pragma unroll
        for (int nt = 0; nt < 4; ++nt) {
            bf16x8 bf = *(const bf16x8*)(W1b + ((size_t)((ch * 4 + lk) * 64) + nt * 16 + lm) * 8);
            acc[nt] = __builtin_amdgcn_mfma_f32_16x16x32_bf16(af, bf, acc[nt], 0, 0, 0);
        }
    }
    int rowbase = blockIdx.x * 64 + wave * 16 + lk * 4;
    // h1 store
#pragma unroll
    for (int nt = 0; nt < 4; ++nt) {
#pragma unroll
        for (int j = 0; j < 4; ++j) {
            int gr = rowbase + j;
            if (gr < Nn) h1[(size_t)gr * 64 + nt * 16 + lm] = acc[nt][j];
        }
    }
    // fused attention dots: alpha_src[n,h] = sum_c h[n,h*8+c]*asrc[h*8+c]
#pragma unroll
    for (int nt = 0; nt < 4; ++nt) {
        float ws = asrc[nt * 16 + lm];
        float wd = adst[nt * 16 + lm];
#pragma unroll
        for (int j = 0; j < 4; ++j) {
            float sv = acc[nt][j] * ws;
            float dv = acc[nt][j] * wd;
            sv += __shfl_xor(sv, 1); dv += __shfl_xor(dv, 1);
            sv += __shfl_xor(sv, 2); dv += __shfl_xor(dv, 2);
            sv += __shfl_xor(sv, 4); dv += __shfl_xor(dv, 4);
            int gr = rowbase + j;
            if ((lm & 7) == 0 && gr < Nn) {
                int hh = nt * 2 + (lm >> 3);
                as1[(size_t)gr * 8 + hh] = sv;
                ad1[(size_t)gr * 8 + hh] = dv;
            }
        }
    }
}

// ---------------------------------------------------------------------------
// CSR build: histogram -> 3-kernel exclusive scan (rowptr + cursor copy) ->
// atomic-cursor scatter. (rank[] eliminated: same atomic count, -13.6MB.)
// ---------------------------------------------------------------------------
__global__ void hist_k(const int* __restrict__ ei, int E, int Nn, int* __restrict__ deg)
{
    int e = blockIdx.x * 256 + threadIdx.x;
    int Ep = E + Nn;
    if (e >= Ep) return;
    int d = (e < E) ? ei[E + e] : e - E;
    atomicAdd(&deg[d], 1);
}

__global__ void scan_a_k(const int* __restrict__ deg, int Nn, int* __restrict__ bsum)
{
    __shared__ int tmp[256];
    int t = threadIdx.x;
    int base = blockIdx.x * 1024 + t * 4;
    int s = 0;
#pragma unroll
    for (int j = 0; j < 4; ++j) { int i = base + j; if (i < Nn) s += deg[i]; }
    tmp[t] = s;
    __syncthreads();
    for (int off = 1; off < 256; off <<= 1) {
        int a = (t >= off) ? tmp[t - off] : 0;
        __syncthreads();
        tmp[t] += a;
        __syncthreads();
    }
    if (t == 255) bsum[blockIdx.x] = tmp[255];
}

__global__ void scan_b_k(int* __restrict__ bsum, int nb)
{
    __shared__ int tmp[256];
    int t = threadIdx.x;
    int v = (t < nb) ? bsum[t] : 0;
    tmp[t] = v;
    __syncthreads();
    for (int off = 1; off < 256; off <<= 1) {
        int a = (t >= off) ? tmp[t - off] : 0;
        __syncthreads();
        tmp[t] += a;
        __syncthreads();
    }
    if (t < nb) bsum[t] = tmp[t] - v;  // exclusive
}

__global__ void scan_c_k(const int* __restrict__ deg, int Nn, const int* __restrict__ boff,
                         int* __restrict__ rowptr, int* __restrict__ cur)
{
    __shared__ int tmp[256];
    int t = threadIdx.x;
    int base = blockIdx.x * 1024 + t * 4;
    int v[4];
    int s = 0;
#pragma unroll
    for (int j = 0; j < 4; ++j) {
        int i = base + j;
        v[j] = (i < Nn) ? deg[i] : 0;
        s += v[j];
    }
    tmp[t] = s;
    __syncthreads();
    for (int off = 1; off < 256; off <<= 1) {
        int a = (t >= off) ? tmp[t - off] : 0;
        __syncthreads();
        tmp[t] += a;
        __syncthreads();
    }
    int excl = boff[blockIdx.x] + tmp[t] - s;
#pragma unroll
    for (int j = 0; j < 4; ++j) {
        int i = base + j;
        if (i < Nn) {
            rowptr[i] = excl;
            cur[i] = excl;
            excl += v[j];
            if (i == Nn - 1) rowptr[Nn] = excl;
        }
    }
}

__global__ void scat_k(const int* __restrict__ ei, int E, int Nn,
                       int* __restrict__ cur, int* __restrict__ csr)
{
    int e = blockIdx.x * 256 + threadIdx.x;
    int Ep = E + Nn;
    if (e >= Ep) return;
    int s, d;
    if (e < E) { s = ei[e]; d = ei[E + e]; } else { s = d = e - E; }
    int pos = atomicAdd(&cur[d], 1);
    csr[pos] = s;
}

// ---------------------------------------------------------------------------
// Layer-1 fused softmax+aggregate + node2 (bias+ELU+GEMM2(64x10)+layer-2
// attention dots): one wave per dst node. After the xor-16/32 butterfly ALL
// lanes hold the reduced row, so the 64->10 matvec runs right in the
// epilogue (W2 staged in LDS), killing the out1 round-trip (51.2MB).
// ---------------------------------------------------------------------------
__global__ __launch_bounds__(256) void agg1n_k(const int* __restrict__ csr,
                                               const int* __restrict__ rowptr,
                                               const float* __restrict__ as1,
                                               const float* __restrict__ ad1,
                                               const float* __restrict__ h1,
                                               const float* __restrict__ b1,
                                               const float* __restrict__ W2,
                                               const float* __restrict__ as2w,
                                               const float* __restrict__ ad2w,
                                               float* __restrict__ h2,
                                               float* __restrict__ as2,
                                               float* __restrict__ ad2, int Nn)
{
    __shared__ float W2s[640];
    for (int i = threadIdx.x; i < 640; i += 256) W2s[i] = W2[i];
    __syncthreads();   // before any early exit (divergent-barrier safety)

    int wid = (blockIdx.x * 256 + threadIdx.x) >> 6;
    if (wid >= Nn) return;
    int lane = threadIdx.x & 63;
    int sub = lane >> 4;
    int c4 = lane & 15;
    int h = c4 >> 1;
    float adv = ad1[wid * 8 + h];
    int start = rowptr[wid];
    int len = rowptr[wid + 1] - start;
    float accp = 0.f;
    float4 accv = make_float4(0.f, 0.f, 0.f, 0.f);
    int i = sub;
    for (; i + 12 < len; i += 16) {
        int s0 = csr[start + i];
        int s1 = csr[start + i + 4];
        int s2 = csr[start + i + 8];
        int s3 = csr[start + i + 12];
        float e0 = as1[s0 * 8 + h] + adv;
        float e1 = as1[s1 * 8 + h] + adv;
        float e2 = as1[s2 * 8 + h] + adv;
        float e3 = as1[s3 * 8 + h] + adv;
        float4 hv0 = *(const float4*)(h1 + (size_t)s0 * 64 + c4 * 4);
        float4 hv1 = *(const float4*)(h1 + (size_t)s1 * 64 + c4 * 4);
        float4 hv2 = *(const float4*)(h1 + (size_t)s2 * 64 + c4 * 4);
        float4 hv3 = *(const float4*)(h1 + (size_t)s3 * 64 + c4 * 4);
        e0 = e0 > 0.f ? e0 : NEG * e0;
        e1 = e1 > 0.f ? e1 : NEG * e1;
        e2 = e2 > 0.f ? e2 : NEG * e2;
        e3 = e3 > 0.f ? e3 : NEG * e3;
        float p0 = __expf(e0), p1 = __expf(e1), p2 = __expf(e2), p3 = __expf(e3);
        accp += (p0 + p1) + (p2 + p3);
        accv.x += p0 * hv0.x + p1 * hv1.x + p2 * hv2.x + p3 * hv3.x;
        accv.y += p0 * hv0.y + p1 * hv1.y + p2 * hv2.y + p3 * hv3.y;
        accv.z += p0 * hv0.z + p1 * hv1.z + p2 * hv2.z + p3 * hv3.z;
        accv.w += p0 * hv0.w + p1 * hv1.w + p2 * hv2.w + p3 * hv3.w;
    }
    for (; i < len; i += 4) {
        int s0 = csr[start + i];
        float e0 = as1[s0 * 8 + h] + adv;
        float4 hv0 = *(const float4*)(h1 + (size_t)s0 * 64 + c4 * 4);
        e0 = e0 > 0.f ? e0 : NEG * e0;
        float p0 = __expf(e0);
        accp += p0;
        accv.x += p0 * hv0.x;
        accv.y += p0 * hv0.y;
        accv.z += p0 * hv0.z;
        accv.w += p0 * hv0.w;
    }
    accp   += __shfl_xor(accp, 16);
    accv.x += __shfl_xor(accv.x, 16);
    accv.y += __shfl_xor(accv.y, 16);
    accv.z += __shfl_xor(accv.z, 16);
    accv.w += __shfl_xor(accv.w, 16);
    accp   += __shfl_xor(accp, 32);
    accv.x += __shfl_xor(accv.x, 32);
    accv.y += __shfl_xor(accv.y, 32);
    accv.z += __shfl_xor(accv.z, 32);
    accv.w += __shfl_xor(accv.w, 32);

    // ---- fused node2: bias + ELU + 64x10 matvec + layer-2 attn dots ----
    float inv = 1.f / (accp + 1e-16f);
    float4 b = *(const float4*)(b1 + c4 * 4);
    float g0 = accv.x * inv + b.x; g0 = g0 > 0.f ? g0 : expm1f(g0);
    float g1 = accv.y * inv + b.y; g1 = g1 > 0.f ? g1 : expm1f(g1);
    float g2 = accv.z * inv + b.z; g2 = g2 > 0.f ? g2 : expm1f(g2);
    float g3 = accv.w * inv + b.w; g3 = g3 > 0.f ? g3 : expm1f(g3);
    int k0 = c4 * 4;
    float aj[10];
#pragma unroll
    for (int j = 0; j < 10; ++j)
        aj[j] = g0 * W2s[(k0 + 0) * 10 + j] + g1 * W2s[(k0 + 1) * 10 + j]
              + g2 * W2s[(k0 + 2) * 10 + j] + g3 * W2s[(k0 + 3) * 10 + j];
#pragma unroll
    for (int m = 1; m <= 8; m <<= 1) {
#pragma unroll
        for (int j = 0; j < 10; ++j) aj[j] += __shfl_xor(aj[j], m);
    }
    if (lane == 0) {
        float s2 = 0.f, d2 = 0.f;
#pragma unroll
        for (int j = 0; j < 10; ++j) { s2 += aj[j] * as2w[j]; d2 += aj[j] * ad2w[j]; }
        *(float4*)(h2 + (size_t)wid * 16 + 0) = make_float4(aj[0], aj[1], aj[2], aj[3]);
        *(float4*)(h2 + (size_t)wid * 16 + 4) = make_float4(aj[4], aj[5], aj[6], aj[7]);
        h2[(size_t)wid * 16 + 8] = aj[8];
        h2[(size_t)wid * 16 + 9] = aj[9];
        as2[wid] = s2;
        ad2[wid] = d2;
    }
}

// ---------------------------------------------------------------------------
// Layer-2 fused softmax+aggregate + bias + log_softmax: one wave per dst.
// After the xor-16/32 reduce all lanes hold the class vector; the 10-class
// log_softmax is two 16-lane butterflies (max, sum). Kills lsm_k.
// ---------------------------------------------------------------------------
__global__ __launch_bounds__(256) void agg2l_k(const int* __restrict__ csr,
                                               const int* __restrict__ rowptr,
                                               const float* __restrict__ as2,
                                               const float* __restrict__ ad2,
                                               const float* __restrict__ h2,
                                               const float* __restrict__ b2,
                                               float* __restrict__ out, int Nn)
{
    int wid = (blockIdx.x * 256 + threadIdx.x) >> 6;
    if (wid >= Nn) return;
    int lane = threadIdx.x & 63;
    int sub = lane >> 4;
    int c = lane & 15;
    float adv = ad2[wid];
    int start = rowptr[wid];
    int len = rowptr[wid + 1] - start;
    float accp = 0.f, accv = 0.f;
    int i = sub;
    for (; i + 12 < len; i += 16) {
        int s0 = csr[start + i];
        int s1 = csr[start + i + 4];
        int s2 = csr[start + i + 8];
        int s3 = csr[start + i + 12];
        float e0 = as2[s0] + adv;
        float e1 = as2[s1] + adv;
        float e2 = as2[s2] + adv;
        float e3 = as2[s3] + adv;
        float v0 = (c < 10) ? h2[(size_t)s0 * 16 + c] : 0.f;
        float v1 = (c < 10) ? h2[(size_t)s1 * 16 + c] : 0.f;
        float v2 = (c < 10) ? h2[(size_t)s2 * 16 + c] : 0.f;
        float v3 = (c < 10) ? h2[(size_t)s3 * 16 + c] : 0.f;
        e0 = e0 > 0.f ? e0 : NEG * e0;
        e1 = e1 > 0.f ? e1 : NEG * e1;
        e2 = e2 > 0.f ? e2 : NEG * e2;
        e3 = e3 > 0.f ? e3 : NEG * e3;
        float p0 = __expf(e0), p1 = __expf(e1), p2 = __expf(e2), p3 = __expf(e3);
        accp += (p0 + p1) + (p2 + p3);
        accv += p0 * v0 + p1 * v1 + p2 * v2 + p3 * v3;
    }
    for (; i < len; i += 4) {
        int s0 = csr[start + i];
        float e0 = as2[s0] + adv;
        float v0 = (c < 10) ? h2[(size_t)s0 * 16 + c] : 0.f;
        e0 = e0 > 0.f ? e0 : NEG * e0;
        float p0 = __expf(e0);
        accp += p0;
        accv += p0 * v0;
    }
    accp += __shfl_xor(accp, 16);
    accv += __shfl_xor(accv, 16);
    accp += __shfl_xor(accp, 32);
    accv += __shfl_xor(accv, 32);

    // ---- fused bias + log_softmax over the 10 classes ----
    float z = (c < 10) ? accv / (accp + 1e-16f) + b2[c] : -1e30f;
    float m = z;
    m = fmaxf(m, __shfl_xor(m, 1));
    m = fmaxf(m, __shfl_xor(m, 2));
    m = fmaxf(m, __shfl_xor(m, 4));
    m = fmaxf(m, __shfl_xor(m, 8));
    float p = (c < 10) ? expf(z - m) : 0.f;
    p += __shfl_xor(p, 1);
    p += __shfl_xor(p, 2);
    p += __shfl_xor(p, 4);
    p += __shfl_xor(p, 8);
    float lse = m + logf(p);
    if (sub == 0 && c < 10)
        out[(size_t)wid * 10 + c] = z - lse;
}

// ---------------------------------------------------------------------------
extern "C" void kernel_launch(void* const* d_in, const int* in_sizes, int n_in,
                              void* d_out, int out_size, void* d_ws, size_t ws_size,
                              hipStream_t stream)
{
    const float* x     = (const float*)d_in[0];
    const float* W1    = (const float*)d_in[1];
    const float* asrc1 = (const float*)d_in[2];
    const float* adst1 = (const float*)d_in[3];
    const float* b1    = (const float*)d_in[4];
    const float* W2    = (const float*)d_in[5];
    const float* asrc2 = (const float*)d_in[6];
    const float* adst2 = (const float*)d_in[7];
    const float* b2    = (const float*)d_in[8];
    const int*   ei    = (const int*)d_in[9];
    float* out = (float*)d_out;

    int F  = in_sizes[1] / 64;       // 512
    int Nn = in_sizes[0] / F;        // 100000
    int E  = in_sizes[9] / 2;        // 1600000
    int Ep = E + Nn;
    int nb = (Nn + 1023) / 1024;

    float* f = (float*)d_ws;
    __bf16* w1b = (__bf16*)f;  f += 512 * 64 / 2;   // 64KB, 16B-aligned
    float* h1   = f;  f += (size_t)Nn * 64;
    float* as1  = f;  f += (size_t)Nn * 8;
    float* ad1  = f;  f += (size_t)Nn * 8;
    float* h2   = f;  f += (size_t)Nn * 16;
    float* as2  = f;  f += Nn;
    float* ad2  = f;  f += Nn;
    int* ip = (int*)f;
    int* deg    = ip;  ip += Nn;
    int* rowptr = ip;  ip += Nn + 1;
    int* bsum   = ip;  ip += 256;
    int* cur    = ip;  ip += Nn;
    int* csr    = ip;  ip += Ep;

    // CSR build (shared by both layers)
    hipMemsetAsync(deg, 0, (size_t)Nn * sizeof(int), stream);
    hist_k<<<(Ep + 255) / 256, 256, 0, stream>>>(ei, E, Nn, deg);
    scan_a_k<<<nb, 256, 0, stream>>>(deg, Nn, bsum);
    scan_b_k<<<1, 256, 0, stream>>>(bsum, nb);
    scan_c_k<<<nb, 256, 0, stream>>>(deg, Nn, bsum, rowptr, cur);
    scat_k<<<(Ep + 255) / 256, 256, 0, stream>>>(ei, E, Nn, cur, csr);

    // Layer 1 (gemm + fused attention dots)
    w1prep_k<<<16, 256, 0, stream>>>(W1, w1b);
    gemm1a_k<<<(Nn + 63) / 64, 256, 0, stream>>>(x, w1b, asrc1, adst1, h1, as1, ad1, Nn);

    // Layer-1 aggregate + fused node2 (bias/ELU/GEMM2/attn2 dots)
    agg1n_k<<<(Nn + 3) / 4, 256, 0, stream>>>(csr, rowptr, as1, ad1, h1,
                                              b1, W2, asrc2, adst2, h2, as2, ad2, Nn);

    // Layer-2 aggregate + fused bias + log_softmax
    agg2l_k<<<(Nn + 3) / 4, 256, 0, stream>>>(csr, rowptr, as2, ad2, h2, b2, out, Nn);
}

// Round 2
// 581.642 us; speedup vs baseline: 1.1523x; 1.1523x over previous
//
#include <hip/hip_runtime.h>
#include <math.h>

#define NEG 0.2f

typedef __bf16 bf16x8 __attribute__((ext_vector_type(8)));
typedef float  f32x4  __attribute__((ext_vector_type(4)));

// ---------------------------------------------------------------------------
// W1 pre-swizzle: W1[512,64] f32 -> W1b bf16 in MFMA B-fragment order.
// Slot i = (ch*4+lk)*64 + n holds 8 bf16: W1[ch*32+lk*8+j][n], j=0..7.
// ---------------------------------------------------------------------------
__global__ void w1prep_k(const float* __restrict__ W1, __bf16* __restrict__ W1b)
{
    int i = blockIdx.x * 256 + threadIdx.x;   // 0..4095
    int n = i & 63;
    int k0 = (i >> 6) * 8;                    // (ch*4+lk)*8 == ch*32+lk*8
#pragma unroll
    for (int j = 0; j < 8; ++j)
        W1b[(size_t)i * 8 + j] = (__bf16)W1[(size_t)(k0 + j) * 64 + n];
}

// ---------------------------------------------------------------------------
// K1: h1[N,64] = x[N,512] @ W1[512,64] via bf16 MFMA (16x16x32), PLUS fused
// per-(node,head) attention dots (as1/ad1) computed from the accumulator
// registers (saves the attn1_k re-read of h1).
// C/D: col = lane&15, row = (lane>>4)*4 + reg (verified m89). For the dots,
// head = col>>3; reduce c=0..7 with shfl_xor 1/2/4 inside each lm&7 group.
// ---------------------------------------------------------------------------
__global__ __launch_bounds__(256, 4) void gemm1a_k(const float* __restrict__ x,
                                                   const __bf16* __restrict__ W1b,
                                                   const float* __restrict__ asrc,
                                                   const float* __restrict__ adst,
                                                   float* __restrict__ h1,
                                                   float* __restrict__ as1,
                                                   float* __restrict__ ad1, int Nn)
{
    int t = threadIdx.x;
    int wave = t >> 6, lane = t & 63;
    int lm = lane & 15, lk = lane >> 4;
    int rowa = blockIdx.x * 64 + wave * 16 + lm;          // A: m = lane&15
    const float* xrow = x + (size_t)(rowa < Nn ? rowa : 0) * 512;
    f32x4 acc[4] = {};
#pragma unroll
    for (int ch = 0; ch < 16; ++ch) {
        float4 a0 = *(const float4*)(xrow + ch * 32 + lk * 8);
        float4 a1 = *(const float4*)(xrow + ch * 32 + lk * 8 + 4);
        bf16x8 af;
        af[0] = (__bf16)a0.x; af[1] = (__bf16)a0.y;
        af[2] = (__bf16)a0.z; af[3] = (__bf16)a0.w;
        af[4] = (__bf16)a1.x; af[5] = (__bf16)a1.y;
        af[6] = (__bf16)a1.z; af[7] = (__bf16)a1.w;
#pragma unroll
        for (int nt = 0; nt < 4; ++nt) {
            bf16x8 bf = *(const bf16x8*)(W1b + ((size_t)((ch * 4 + lk) * 64) + nt * 16 + lm) * 8);
            acc[nt] = __builtin_amdgcn_mfma_f32_16x16x32_bf16(af, bf, acc[nt], 0, 0, 0);
        }
    }
    int rowbase = blockIdx.x * 64 + wave * 16 + lk * 4;
    // h1 store
#pragma unroll
    for (int nt = 0; nt < 4; ++nt) {
#pragma unroll
        for (int j = 0; j < 4; ++j) {
            int gr = rowbase + j;
            if (gr < Nn) h1[(size_t)gr * 64 + nt * 16 + lm] = acc[nt][j];
        }
    }
    // fused attention dots: alpha_src[n,h] = sum_c h[n,h*8+c]*asrc[h*8+c]
#pragma unroll
    for (int nt = 0; nt < 4; ++nt) {
        float ws = asrc[nt * 16 + lm];
        float wd = adst[nt * 16 + lm];
#pragma unroll
        for (int j = 0; j < 4; ++j) {
            float sv = acc[nt][j] * ws;
            float dv = acc[nt][j] * wd;
            sv += __shfl_xor(sv, 1); dv += __shfl_xor(dv, 1);
            sv += __shfl_xor(sv, 2); dv += __shfl_xor(dv, 2);
            sv += __shfl_xor(sv, 4); dv += __shfl_xor(dv, 4);
            int gr = rowbase + j;
            if ((lm & 7) == 0 && gr < Nn) {
                int hh = nt * 2 + (lm >> 3);
                as1[(size_t)gr * 8 + hh] = sv;
                ad1[(size_t)gr * 8 + hh] = dv;
            }
        }
    }
}

// ---------------------------------------------------------------------------
// CSR build (rank-based, proven): fused histogram+rank -> 3-kernel exclusive
// scan -> atomic-free scatter. The scatter's stores carry no dependency on an
// atomic result, so all its memory ops overlap (round-1 lesson: the cursor-
// atomic variant serialized atomic->store and cost +20-30us).
// ---------------------------------------------------------------------------
__global__ void hist_rank_k(const int* __restrict__ ei, int E, int Nn,
                            int* __restrict__ deg, int* __restrict__ rank)
{
    int e = blockIdx.x * 256 + threadIdx.x;
    int Ep = E + Nn;
    if (e >= Ep) return;
    int d = (e < E) ? ei[E + e] : e - E;
    rank[e] = atomicAdd(&deg[d], 1);
}

__global__ void scan_a_k(const int* __restrict__ deg, int Nn, int* __restrict__ bsum)
{
    __shared__ int tmp[256];
    int t = threadIdx.x;
    int base = blockIdx.x * 1024 + t * 4;
    int s = 0;
#pragma unroll
    for (int j = 0; j < 4; ++j) { int i = base + j; if (i < Nn) s += deg[i]; }
    tmp[t] = s;
    __syncthreads();
    for (int off = 1; off < 256; off <<= 1) {
        int a = (t >= off) ? tmp[t - off] : 0;
        __syncthreads();
        tmp[t] += a;
        __syncthreads();
    }
    if (t == 255) bsum[blockIdx.x] = tmp[255];
}

__global__ void scan_b_k(int* __restrict__ bsum, int nb)
{
    __shared__ int tmp[256];
    int t = threadIdx.x;
    int v = (t < nb) ? bsum[t] : 0;
    tmp[t] = v;
    __syncthreads();
    for (int off = 1; off < 256; off <<= 1) {
        int a = (t >= off) ? tmp[t - off] : 0;
        __syncthreads();
        tmp[t] += a;
        __syncthreads();
    }
    if (t < nb) bsum[t] = tmp[t] - v;  // exclusive
}

__global__ void scan_c_k(const int* __restrict__ deg, int Nn, const int* __restrict__ boff,
                         int* __restrict__ rowptr)
{
    __shared__ int tmp[256];
    int t = threadIdx.x;
    int base = blockIdx.x * 1024 + t * 4;
    int v[4];
    int s = 0;
#pragma unroll
    for (int j = 0; j < 4; ++j) {
        int i = base + j;
        v[j] = (i < Nn) ? deg[i] : 0;
        s += v[j];
    }
    tmp[t] = s;
    __syncthreads();
    for (int off = 1; off < 256; off <<= 1) {
        int a = (t >= off) ? tmp[t - off] : 0;
        __syncthreads();
        tmp[t] += a;
        __syncthreads();
    }
    int excl = boff[blockIdx.x] + tmp[t] - s;
#pragma unroll
    for (int j = 0; j < 4; ++j) {
        int i = base + j;
        if (i < Nn) {
            rowptr[i] = excl;
            excl += v[j];
            if (i == Nn - 1) rowptr[Nn] = excl;
        }
    }
}

__global__ void scat2_k(const int* __restrict__ ei, int E, int Nn,
                        const int* __restrict__ rowptr, const int* __restrict__ rank,
                        int* __restrict__ csr)
{
    int e = blockIdx.x * 256 + threadIdx.x;
    int Ep = E + Nn;
    if (e >= Ep) return;
    int s, d;
    if (e < E) { s = ei[e]; d = ei[E + e]; } else { s = d = e - E; }
    csr[rowptr[d] + rank[e]] = s;
}

// ---------------------------------------------------------------------------
// Layer-1 fused softmax+aggregate + node2 (bias+ELU+GEMM2(64x10)+layer-2
// attention dots): one wave per dst node. After the xor-16/32 butterfly ALL
// lanes hold the reduced row, so the 64->10 matvec runs right in the
// epilogue (W2 staged in LDS), killing the out1 round-trip (51.2MB).
// launch_bounds(256,4): cap VGPR<=128 so the fused epilogue cannot cost
// occupancy in the latency-bound gather loop (spills, if any, are epilogue-
// only, once per wave).
// ---------------------------------------------------------------------------
__global__ __launch_bounds__(256, 4) void agg1n_k(const int* __restrict__ csr,
                                                  const int* __restrict__ rowptr,
                                                  const float* __restrict__ as1,
                                                  const float* __restrict__ ad1,
                                                  const float* __restrict__ h1,
                                                  const float* __restrict__ b1,
                                                  const float* __restrict__ W2,
                                                  const float* __restrict__ as2w,
                                                  const float* __restrict__ ad2w,
                                                  float* __restrict__ h2,
                                                  float* __restrict__ as2,
                                                  float* __restrict__ ad2, int Nn)
{
    __shared__ float W2s[640];
    for (int i = threadIdx.x; i < 640; i += 256) W2s[i] = W2[i];
    __syncthreads();   // before any early exit (divergent-barrier safety)

    int wid = (blockIdx.x * 256 + threadIdx.x) >> 6;
    if (wid >= Nn) return;
    int lane = threadIdx.x & 63;
    int sub = lane >> 4;
    int c4 = lane & 15;
    int h = c4 >> 1;
    float adv = ad1[wid * 8 + h];
    int start = rowptr[wid];
    int len = rowptr[wid + 1] - start;
    float accp = 0.f;
    float4 accv = make_float4(0.f, 0.f, 0.f, 0.f);
    int i = sub;
    for (; i + 12 < len; i += 16) {
        int s0 = csr[start + i];
        int s1 = csr[start + i + 4];
        int s2 = csr[start + i + 8];
        int s3 = csr[start + i + 12];
        float e0 = as1[s0 * 8 + h] + adv;
        float e1 = as1[s1 * 8 + h] + adv;
        float e2 = as1[s2 * 8 + h] + adv;
        float e3 = as1[s3 * 8 + h] + adv;
        float4 hv0 = *(const float4*)(h1 + (size_t)s0 * 64 + c4 * 4);
        float4 hv1 = *(const float4*)(h1 + (size_t)s1 * 64 + c4 * 4);
        float4 hv2 = *(const float4*)(h1 + (size_t)s2 * 64 + c4 * 4);
        float4 hv3 = *(const float4*)(h1 + (size_t)s3 * 64 + c4 * 4);
        e0 = e0 > 0.f ? e0 : NEG * e0;
        e1 = e1 > 0.f ? e1 : NEG * e1;
        e2 = e2 > 0.f ? e2 : NEG * e2;
        e3 = e3 > 0.f ? e3 : NEG * e3;
        float p0 = __expf(e0), p1 = __expf(e1), p2 = __expf(e2), p3 = __expf(e3);
        accp += (p0 + p1) + (p2 + p3);
        accv.x += p0 * hv0.x + p1 * hv1.x + p2 * hv2.x + p3 * hv3.x;
        accv.y += p0 * hv0.y + p1 * hv1.y + p2 * hv2.y + p3 * hv3.y;
        accv.z += p0 * hv0.z + p1 * hv1.z + p2 * hv2.z + p3 * hv3.z;
        accv.w += p0 * hv0.w + p1 * hv1.w + p2 * hv2.w + p3 * hv3.w;
    }
    for (; i < len; i += 4) {
        int s0 = csr[start + i];
        float e0 = as1[s0 * 8 + h] + adv;
        float4 hv0 = *(const float4*)(h1 + (size_t)s0 * 64 + c4 * 4);
        e0 = e0 > 0.f ? e0 : NEG * e0;
        float p0 = __expf(e0);
        accp += p0;
        accv.x += p0 * hv0.x;
        accv.y += p0 * hv0.y;
        accv.z += p0 * hv0.z;
        accv.w += p0 * hv0.w;
    }
    accp   += __shfl_xor(accp, 16);
    accv.x += __shfl_xor(accv.x, 16);
    accv.y += __shfl_xor(accv.y, 16);
    accv.z += __shfl_xor(accv.z, 16);
    accv.w += __shfl_xor(accv.w, 16);
    accp   += __shfl_xor(accp, 32);
    accv.x += __shfl_xor(accv.x, 32);
    accv.y += __shfl_xor(accv.y, 32);
    accv.z += __shfl_xor(accv.z, 32);
    accv.w += __shfl_xor(accv.w, 32);

    // ---- fused node2: bias + ELU + 64x10 matvec + layer-2 attn dots ----
    float inv = 1.f / (accp + 1e-16f);
    float4 b = *(const float4*)(b1 + c4 * 4);
    float g0 = accv.x * inv + b.x; g0 = g0 > 0.f ? g0 : expm1f(g0);
    float g1 = accv.y * inv + b.y; g1 = g1 > 0.f ? g1 : expm1f(g1);
    float g2 = accv.z * inv + b.z; g2 = g2 > 0.f ? g2 : expm1f(g2);
    float g3 = accv.w * inv + b.w; g3 = g3 > 0.f ? g3 : expm1f(g3);
    int k0 = c4 * 4;
    float aj[10];
#pragma unroll
    for (int j = 0; j < 10; ++j)
        aj[j] = g0 * W2s[(k0 + 0) * 10 + j] + g1 * W2s[(k0 + 1) * 10 + j]
              + g2 * W2s[(k0 + 2) * 10 + j] + g3 * W2s[(k0 + 3) * 10 + j];
#pragma unroll
    for (int m = 1; m <= 8; m <<= 1) {
#pragma unroll
        for (int j = 0; j < 10; ++j) aj[j] += __shfl_xor(aj[j], m);
    }
    if (lane == 0) {
        float s2 = 0.f, d2 = 0.f;
#pragma unroll
        for (int j = 0; j < 10; ++j) { s2 += aj[j] * as2w[j]; d2 += aj[j] * ad2w[j]; }
        *(float4*)(h2 + (size_t)wid * 16 + 0) = make_float4(aj[0], aj[1], aj[2], aj[3]);
        *(float4*)(h2 + (size_t)wid * 16 + 4) = make_float4(aj[4], aj[5], aj[6], aj[7]);
        h2[(size_t)wid * 16 + 8] = aj[8];
        h2[(size_t)wid * 16 + 9] = aj[9];
        as2[wid] = s2;
        ad2[wid] = d2;
    }
}

// ---------------------------------------------------------------------------
// Layer-2 fused softmax+aggregate + bias + log_softmax: one wave per dst.
// After the xor-16/32 reduce all lanes hold the class vector; the 10-class
// log_softmax is two 16-lane butterflies (max, sum). Kills lsm_k.
// ---------------------------------------------------------------------------
__global__ __launch_bounds__(256) void agg2l_k(const int* __restrict__ csr,
                                               const int* __restrict__ rowptr,
                                               const float* __restrict__ as2,
                                               const float* __restrict__ ad2,
                                               const float* __restrict__ h2,
                                               const float* __restrict__ b2,
                                               float* __restrict__ out, int Nn)
{
    int wid = (blockIdx.x * 256 + threadIdx.x) >> 6;
    if (wid >= Nn) return;
    int lane = threadIdx.x & 63;
    int sub = lane >> 4;
    int c = lane & 15;
    float adv = ad2[wid];
    int start = rowptr[wid];
    int len = rowptr[wid + 1] - start;
    float accp = 0.f, accv = 0.f;
    int i = sub;
    for (; i + 12 < len; i += 16) {
        int s0 = csr[start + i];
        int s1 = csr[start + i + 4];
        int s2 = csr[start + i + 8];
        int s3 = csr[start + i + 12];
        float e0 = as2[s0] + adv;
        float e1 = as2[s1] + adv;
        float e2 = as2[s2] + adv;
        float e3 = as2[s3] + adv;
        float v0 = (c < 10) ? h2[(size_t)s0 * 16 + c] : 0.f;
        float v1 = (c < 10) ? h2[(size_t)s1 * 16 + c] : 0.f;
        float v2 = (c < 10) ? h2[(size_t)s2 * 16 + c] : 0.f;
        float v3 = (c < 10) ? h2[(size_t)s3 * 16 + c] : 0.f;
        e0 = e0 > 0.f ? e0 : NEG * e0;
        e1 = e1 > 0.f ? e1 : NEG * e1;
        e2 = e2 > 0.f ? e2 : NEG * e2;
        e3 = e3 > 0.f ? e3 : NEG * e3;
        float p0 = __expf(e0), p1 = __expf(e1), p2 = __expf(e2), p3 = __expf(e3);
        accp += (p0 + p1) + (p2 + p3);
        accv += p0 * v0 + p1 * v1 + p2 * v2 + p3 * v3;
    }
    for (; i < len; i += 4) {
        int s0 = csr[start + i];
        float e0 = as2[s0] + adv;
        float v0 = (c < 10) ? h2[(size_t)s0 * 16 + c] : 0.f;
        e0 = e0 > 0.f ? e0 : NEG * e0;
        float p0 = __expf(e0);
        accp += p0;
        accv += p0 * v0;
    }
    accp += __shfl_xor(accp, 16);
    accv += __shfl_xor(accv, 16);
    accp += __shfl_xor(accp, 32);
    accv += __shfl_xor(accv, 32);

    // ---- fused bias + log_softmax over the 10 classes ----
    float z = (c < 10) ? accv / (accp + 1e-16f) + b2[c] : -1e30f;
    float m = z;
    m = fmaxf(m, __shfl_xor(m, 1));
    m = fmaxf(m, __shfl_xor(m, 2));
    m = fmaxf(m, __shfl_xor(m, 4));
    m = fmaxf(m, __shfl_xor(m, 8));
    float p = (c < 10) ? expf(z - m) : 0.f;
    p += __shfl_xor(p, 1);
    p += __shfl_xor(p, 2);
    p += __shfl_xor(p, 4);
    p += __shfl_xor(p, 8);
    float lse = m + logf(p);
    if (sub == 0 && c < 10)
        out[(size_t)wid * 10 + c] = z - lse;
}

// ---------------------------------------------------------------------------
extern "C" void kernel_launch(void* const* d_in, const int* in_sizes, int n_in,
                              void* d_out, int out_size, void* d_ws, size_t ws_size,
                              hipStream_t stream)
{
    const float* x     = (const float*)d_in[0];
    const float* W1    = (const float*)d_in[1];
    const float* asrc1 = (const float*)d_in[2];
    const float* adst1 = (const float*)d_in[3];
    const float* b1    = (const float*)d_in[4];
    const float* W2    = (const float*)d_in[5];
    const float* asrc2 = (const float*)d_in[6];
    const float* adst2 = (const float*)d_in[7];
    const float* b2    = (const float*)d_in[8];
    const int*   ei    = (const int*)d_in[9];
    float* out = (float*)d_out;

    int F  = in_sizes[1] / 64;       // 512
    int Nn = in_sizes[0] / F;        // 100000
    int E  = in_sizes[9] / 2;        // 1600000
    int Ep = E + Nn;
    int nb = (Nn + 1023) / 1024;

    float* f = (float*)d_ws;
    __bf16* w1b = (__bf16*)f;  f += 512 * 64 / 2;   // 64KB, 16B-aligned
    float* h1   = f;  f += (size_t)Nn * 64;
    float* as1  = f;  f += (size_t)Nn * 8;
    float* ad1  = f;  f += (size_t)Nn * 8;
    float* h2   = f;  f += (size_t)Nn * 16;
    float* as2  = f;  f += Nn;
    float* ad2  = f;  f += Nn;
    int* ip = (int*)f;
    int* deg    = ip;  ip += Nn;
    int* rowptr = ip;  ip += Nn + 1;
    int* bsum   = ip;  ip += 256;
    int* rank   = ip;  ip += Ep;
    int* csr    = ip;  ip += Ep;

    // CSR build (shared by both layers) — rank-based, atomic-free scatter
    hipMemsetAsync(deg, 0, (size_t)Nn * sizeof(int), stream);
    hist_rank_k<<<(Ep + 255) / 256, 256, 0, stream>>>(ei, E, Nn, deg, rank);
    scan_a_k<<<nb, 256, 0, stream>>>(deg, Nn, bsum);
    scan_b_k<<<1, 256, 0, stream>>>(bsum, nb);
    scan_c_k<<<nb, 256, 0, stream>>>(deg, Nn, bsum, rowptr);
    scat2_k<<<(Ep + 255) / 256, 256, 0, stream>>>(ei, E, Nn, rowptr, rank, csr);

    // Layer 1 (gemm + fused attention dots)
    w1prep_k<<<16, 256, 0, stream>>>(W1, w1b);
    gemm1a_k<<<(Nn + 63) / 64, 256, 0, stream>>>(x, w1b, asrc1, adst1, h1, as1, ad1, Nn);

    // Layer-1 aggregate + fused node2 (bias/ELU/GEMM2/attn2 dots)
    agg1n_k<<<(Nn + 3) / 4, 256, 0, stream>>>(csr, rowptr, as1, ad1, h1,
                                              b1, W2, asrc2, adst2, h2, as2, ad2, Nn);

    // Layer-2 aggregate + fused bias + log_softmax
    agg2l_k<<<(Nn + 3) / 4, 256, 0, stream>>>(csr, rowptr, as2, ad2, h2, b2, out, Nn);
}

// Round 3
// 578.551 us; speedup vs baseline: 1.1585x; 1.0053x over previous
//
#include <hip/hip_runtime.h>
#include <math.h>

#define NEG 0.2f

typedef __bf16 bf16x8 __attribute__((ext_vector_type(8)));
typedef float  f32x4  __attribute__((ext_vector_type(4)));

// ---------------------------------------------------------------------------
// Fused: W1 pre-swizzle (blocks 0..15) + histogram+rank (remaining blocks).
// Independent workloads; fusing saves a launch and lets the tiny w1prep ride
// along with the atomic histogram.
// W1b slot i = (ch*4+lk)*64 + n holds 8 bf16: W1[ch*32+lk*8+j][n], j=0..7.
// ---------------------------------------------------------------------------
__global__ void histw1_k(const int* __restrict__ ei, int E, int Nn,
                         int* __restrict__ deg, int* __restrict__ rank,
                         const float* __restrict__ W1, __bf16* __restrict__ W1b)
{
    if (blockIdx.x < 16) {
        int i = blockIdx.x * 256 + threadIdx.x;   // 0..4095
        int n = i & 63;
        int k0 = (i >> 6) * 8;                    // (ch*4+lk)*8 == ch*32+lk*8
#pragma unroll
        for (int j = 0; j < 8; ++j)
            W1b[(size_t)i * 8 + j] = (__bf16)W1[(size_t)(k0 + j) * 64 + n];
        return;
    }
    int e = (blockIdx.x - 16) * 256 + threadIdx.x;
    int Ep = E + Nn;
    if (e >= Ep) return;
    int d = (e < E) ? ei[E + e] : e - E;
    rank[e] = atomicAdd(&deg[d], 1);
}

__global__ void scan_a_k(const int* __restrict__ deg, int Nn, int* __restrict__ bsum)
{
    __shared__ int tmp[256];
    int t = threadIdx.x;
    int base = blockIdx.x * 1024 + t * 4;
    int s = 0;
#pragma unroll
    for (int j = 0; j < 4; ++j) { int i = base + j; if (i < Nn) s += deg[i]; }
    tmp[t] = s;
    __syncthreads();
    for (int off = 1; off < 256; off <<= 1) {
        int a = (t >= off) ? tmp[t - off] : 0;
        __syncthreads();
        tmp[t] += a;
        __syncthreads();
    }
    if (t == 255) bsum[blockIdx.x] = tmp[255];
}

__global__ void scan_b_k(int* __restrict__ bsum, int nb)
{
    __shared__ int tmp[256];
    int t = threadIdx.x;
    int v = (t < nb) ? bsum[t] : 0;
    tmp[t] = v;
    __syncthreads();
    for (int off = 1; off < 256; off <<= 1) {
        int a = (t >= off) ? tmp[t - off] : 0;
        __syncthreads();
        tmp[t] += a;
        __syncthreads();
    }
    if (t < nb) bsum[t] = tmp[t] - v;  // exclusive
}

__global__ void scan_c_k(const int* __restrict__ deg, int Nn, const int* __restrict__ boff,
                         int* __restrict__ rowptr)
{
    __shared__ int tmp[256];
    int t = threadIdx.x;
    int base = blockIdx.x * 1024 + t * 4;
    int v[4];
    int s = 0;
#pragma unroll
    for (int j = 0; j < 4; ++j) {
        int i = base + j;
        v[j] = (i < Nn) ? deg[i] : 0;
        s += v[j];
    }
    tmp[t] = s;
    __syncthreads();
    for (int off = 1; off < 256; off <<= 1) {
        int a = (t >= off) ? tmp[t - off] : 0;
        __syncthreads();
        tmp[t] += a;
        __syncthreads();
    }
    int excl = boff[blockIdx.x] + tmp[t] - s;
#pragma unroll
    for (int j = 0; j < 4; ++j) {
        int i = base + j;
        if (i < Nn) {
            rowptr[i] = excl;
            excl += v[j];
            if (i == Nn - 1) rowptr[Nn] = excl;
        }
    }
}

// ---------------------------------------------------------------------------
// Fused: gemm1 (+attention dots) on blocks [0,nbG) + atomic-free CSR scatter
// on blocks [nbG,..). The scatter is latency-bound (scattered 4B stores, 11%
// HBM, 0.4% VALU); the GEMM is MFMA/BW-bound. Interleaving them on the same
// CUs fills each other's stall cycles: sequential ~70+50us -> overlapped
// ~max+eps. Gemm blocks dispatched first so the x-stream saturates early.
//
// GEMM: h1[N,64] = x[N,512] @ W1[512,64] via bf16 MFMA (16x16x32).
// C/D: col = lane&15, row = (lane>>4)*4 + reg (verified m89). Attention dots
// reduced in-register via shfl_xor 1/2/4 within each 8-col head group.
// ---------------------------------------------------------------------------
__global__ __launch_bounds__(256, 4) void scatgemm_k(
    const float* __restrict__ x, const __bf16* __restrict__ W1b,
    const float* __restrict__ asrc, const float* __restrict__ adst,
    float* __restrict__ h1, float* __restrict__ as1, float* __restrict__ ad1,
    const int* __restrict__ ei, int E,
    const int* __restrict__ rowptr, const int* __restrict__ rank,
    int* __restrict__ csr, int Nn, int nbG)
{
    if ((int)blockIdx.x >= nbG) {
        // ---- scatter path ----
        int e = ((int)blockIdx.x - nbG) * 256 + threadIdx.x;
        int Ep = E + Nn;
        if (e >= Ep) return;
        int s, d;
        if (e < E) { s = ei[e]; d = ei[E + e]; } else { s = d = e - E; }
        csr[rowptr[d] + rank[e]] = s;
        return;
    }
    // ---- gemm path ----
    int t = threadIdx.x;
    int wave = t >> 6, lane = t & 63;
    int lm = lane & 15, lk = lane >> 4;
    int rowa = blockIdx.x * 64 + wave * 16 + lm;          // A: m = lane&15
    const float* xrow = x + (size_t)(rowa < Nn ? rowa : 0) * 512;
    f32x4 acc[4] = {};
#pragma unroll
    for (int ch = 0; ch < 16; ++ch) {
        float4 a0 = *(const float4*)(xrow + ch * 32 + lk * 8);
        float4 a1 = *(const float4*)(xrow + ch * 32 + lk * 8 + 4);
        bf16x8 af;
        af[0] = (__bf16)a0.x; af[1] = (__bf16)a0.y;
        af[2] = (__bf16)a0.z; af[3] = (__bf16)a0.w;
        af[4] = (__bf16)a1.x; af[5] = (__bf16)a1.y;
        af[6] = (__bf16)a1.z; af[7] = (__bf16)a1.w;
#pragma unroll
        for (int nt = 0; nt < 4; ++nt) {
            bf16x8 bf = *(const bf16x8*)(W1b + ((size_t)((ch * 4 + lk) * 64) + nt * 16 + lm) * 8);
            acc[nt] = __builtin_amdgcn_mfma_f32_16x16x32_bf16(af, bf, acc[nt], 0, 0, 0);
        }
    }
    int rowbase = blockIdx.x * 64 + wave * 16 + lk * 4;
    // h1 store
#pragma unroll
    for (int nt = 0; nt < 4; ++nt) {
#pragma unroll
        for (int j = 0; j < 4; ++j) {
            int gr = rowbase + j;
            if (gr < Nn) h1[(size_t)gr * 64 + nt * 16 + lm] = acc[nt][j];
        }
    }
    // fused attention dots: alpha_src[n,h] = sum_c h[n,h*8+c]*asrc[h*8+c]
#pragma unroll
    for (int nt = 0; nt < 4; ++nt) {
        float ws = asrc[nt * 16 + lm];
        float wd = adst[nt * 16 + lm];
#pragma unroll
        for (int j = 0; j < 4; ++j) {
            float sv = acc[nt][j] * ws;
            float dv = acc[nt][j] * wd;
            sv += __shfl_xor(sv, 1); dv += __shfl_xor(dv, 1);
            sv += __shfl_xor(sv, 2); dv += __shfl_xor(dv, 2);
            sv += __shfl_xor(sv, 4); dv += __shfl_xor(dv, 4);
            int gr = rowbase + j;
            if ((lm & 7) == 0 && gr < Nn) {
                int hh = nt * 2 + (lm >> 3);
                as1[(size_t)gr * 8 + hh] = sv;
                ad1[(size_t)gr * 8 + hh] = dv;
            }
        }
    }
}

// ---------------------------------------------------------------------------
// Layer-1 fused softmax+aggregate + node2 (bias+ELU+GEMM2(64x10)+layer-2
// attention dots): one wave per dst node. After the xor-16/32 butterfly ALL
// lanes hold the reduced row, so the 64->10 matvec runs right in the
// epilogue (W2 staged in LDS), killing the out1 round-trip (51.2MB).
// ---------------------------------------------------------------------------
__global__ __launch_bounds__(256, 4) void agg1n_k(const int* __restrict__ csr,
                                                  const int* __restrict__ rowptr,
                                                  const float* __restrict__ as1,
                                                  const float* __restrict__ ad1,
                                                  const float* __restrict__ h1,
                                                  const float* __restrict__ b1,
                                                  const float* __restrict__ W2,
                                                  const float* __restrict__ as2w,
                                                  const float* __restrict__ ad2w,
                                                  float* __restrict__ h2,
                                                  float* __restrict__ as2,
                                                  float* __restrict__ ad2, int Nn)
{
    __shared__ float W2s[640];
    for (int i = threadIdx.x; i < 640; i += 256) W2s[i] = W2[i];
    __syncthreads();   // before any early exit (divergent-barrier safety)

    int wid = (blockIdx.x * 256 + threadIdx.x) >> 6;
    if (wid >= Nn) return;
    int lane = threadIdx.x & 63;
    int sub = lane >> 4;
    int c4 = lane & 15;
    int h = c4 >> 1;
    float adv = ad1[wid * 8 + h];
    int start = rowptr[wid];
    int len = rowptr[wid + 1] - start;
    float accp = 0.f;
    float4 accv = make_float4(0.f, 0.f, 0.f, 0.f);
    int i = sub;
    for (; i + 12 < len; i += 16) {
        int s0 = csr[start + i];
        int s1 = csr[start + i + 4];
        int s2 = csr[start + i + 8];
        int s3 = csr[start + i + 12];
        float e0 = as1[s0 * 8 + h] + adv;
        float e1 = as1[s1 * 8 + h] + adv;
        float e2 = as1[s2 * 8 + h] + adv;
        float e3 = as1[s3 * 8 + h] + adv;
        float4 hv0 = *(const float4*)(h1 + (size_t)s0 * 64 + c4 * 4);
        float4 hv1 = *(const float4*)(h1 + (size_t)s1 * 64 + c4 * 4);
        float4 hv2 = *(const float4*)(h1 + (size_t)s2 * 64 + c4 * 4);
        float4 hv3 = *(const float4*)(h1 + (size_t)s3 * 64 + c4 * 4);
        e0 = e0 > 0.f ? e0 : NEG * e0;
        e1 = e1 > 0.f ? e1 : NEG * e1;
        e2 = e2 > 0.f ? e2 : NEG * e2;
        e3 = e3 > 0.f ? e3 : NEG * e3;
        float p0 = __expf(e0), p1 = __expf(e1), p2 = __expf(e2), p3 = __expf(e3);
        accp += (p0 + p1) + (p2 + p3);
        accv.x += p0 * hv0.x + p1 * hv1.x + p2 * hv2.x + p3 * hv3.x;
        accv.y += p0 * hv0.y + p1 * hv1.y + p2 * hv2.y + p3 * hv3.y;
        accv.z += p0 * hv0.z + p1 * hv1.z + p2 * hv2.z + p3 * hv3.z;
        accv.w += p0 * hv0.w + p1 * hv1.w + p2 * hv2.w + p3 * hv3.w;
    }
    for (; i < len; i += 4) {
        int s0 = csr[start + i];
        float e0 = as1[s0 * 8 + h] + adv;
        float4 hv0 = *(const float4*)(h1 + (size_t)s0 * 64 + c4 * 4);
        e0 = e0 > 0.f ? e0 : NEG * e0;
        float p0 = __expf(e0);
        accp += p0;
        accv.x += p0 * hv0.x;
        accv.y += p0 * hv0.y;
        accv.z += p0 * hv0.z;
        accv.w += p0 * hv0.w;
    }
    accp   += __shfl_xor(accp, 16);
    accv.x += __shfl_xor(accv.x, 16);
    accv.y += __shfl_xor(accv.y, 16);
    accv.z += __shfl_xor(accv.z, 16);
    accv.w += __shfl_xor(accv.w, 16);
    accp   += __shfl_xor(accp, 32);
    accv.x += __shfl_xor(accv.x, 32);
    accv.y += __shfl_xor(accv.y, 32);
    accv.z += __shfl_xor(accv.z, 32);
    accv.w += __shfl_xor(accv.w, 32);

    // ---- fused node2: bias + ELU + 64x10 matvec + layer-2 attn dots ----
    float inv = 1.f / (accp + 1e-16f);
    float4 b = *(const float4*)(b1 + c4 * 4);
    float g0 = accv.x * inv + b.x; g0 = g0 > 0.f ? g0 : expm1f(g0);
    float g1 = accv.y * inv + b.y; g1 = g1 > 0.f ? g1 : expm1f(g1);
    float g2 = accv.z * inv + b.z; g2 = g2 > 0.f ? g2 : expm1f(g2);
    float g3 = accv.w * inv + b.w; g3 = g3 > 0.f ? g3 : expm1f(g3);
    int k0 = c4 * 4;
    float aj[10];
#pragma unroll
    for (int j = 0; j < 10; ++j)
        aj[j] = g0 * W2s[(k0 + 0) * 10 + j] + g1 * W2s[(k0 + 1) * 10 + j]
              + g2 * W2s[(k0 + 2) * 10 + j] + g3 * W2s[(k0 + 3) * 10 + j];
#pragma unroll
    for (int m = 1; m <= 8; m <<= 1) {
#pragma unroll
        for (int j = 0; j < 10; ++j) aj[j] += __shfl_xor(aj[j], m);
    }
    if (lane == 0) {
        float s2 = 0.f, d2 = 0.f;
#pragma unroll
        for (int j = 0; j < 10; ++j) { s2 += aj[j] * as2w[j]; d2 += aj[j] * ad2w[j]; }
        *(float4*)(h2 + (size_t)wid * 16 + 0) = make_float4(aj[0], aj[1], aj[2], aj[3]);
        *(float4*)(h2 + (size_t)wid * 16 + 4) = make_float4(aj[4], aj[5], aj[6], aj[7]);
        h2[(size_t)wid * 16 + 8] = aj[8];
        h2[(size_t)wid * 16 + 9] = aj[9];
        as2[wid] = s2;
        ad2[wid] = d2;
    }
}

// ---------------------------------------------------------------------------
// Layer-2 fused softmax+aggregate + bias + log_softmax: one wave per dst.
// After the xor-16/32 reduce all lanes hold the class vector; the 10-class
// log_softmax is two 16-lane butterflies (max, sum).
// ---------------------------------------------------------------------------
__global__ __launch_bounds__(256) void agg2l_k(const int* __restrict__ csr,
                                               const int* __restrict__ rowptr,
                                               const float* __restrict__ as2,
                                               const float* __restrict__ ad2,
                                               const float* __restrict__ h2,
                                               const float* __restrict__ b2,
                                               float* __restrict__ out, int Nn)
{
    int wid = (blockIdx.x * 256 + threadIdx.x) >> 6;
    if (wid >= Nn) return;
    int lane = threadIdx.x & 63;
    int sub = lane >> 4;
    int c = lane & 15;
    float adv = ad2[wid];
    int start = rowptr[wid];
    int len = rowptr[wid + 1] - start;
    float accp = 0.f, accv = 0.f;
    int i = sub;
    for (; i + 12 < len; i += 16) {
        int s0 = csr[start + i];
        int s1 = csr[start + i + 4];
        int s2 = csr[start + i + 8];
        int s3 = csr[start + i + 12];
        float e0 = as2[s0] + adv;
        float e1 = as2[s1] + adv;
        float e2 = as2[s2] + adv;
        float e3 = as2[s3] + adv;
        float v0 = (c < 10) ? h2[(size_t)s0 * 16 + c] : 0.f;
        float v1 = (c < 10) ? h2[(size_t)s1 * 16 + c] : 0.f;
        float v2 = (c < 10) ? h2[(size_t)s2 * 16 + c] : 0.f;
        float v3 = (c < 10) ? h2[(size_t)s3 * 16 + c] : 0.f;
        e0 = e0 > 0.f ? e0 : NEG * e0;
        e1 = e1 > 0.f ? e1 : NEG * e1;
        e2 = e2 > 0.f ? e2 : NEG * e2;
        e3 = e3 > 0.f ? e3 : NEG * e3;
        float p0 = __expf(e0), p1 = __expf(e1), p2 = __expf(e2), p3 = __expf(e3);
        accp += (p0 + p1) + (p2 + p3);
        accv += p0 * v0 + p1 * v1 + p2 * v2 + p3 * v3;
    }
    for (; i < len; i += 4) {
        int s0 = csr[start + i];
        float e0 = as2[s0] + adv;
        float v0 = (c < 10) ? h2[(size_t)s0 * 16 + c] : 0.f;
        e0 = e0 > 0.f ? e0 : NEG * e0;
        float p0 = __expf(e0);
        accp += p0;
        accv += p0 * v0;
    }
    accp += __shfl_xor(accp, 16);
    accv += __shfl_xor(accv, 16);
    accp += __shfl_xor(accp, 32);
    accv += __shfl_xor(accv, 32);

    // ---- fused bias + log_softmax over the 10 classes ----
    float z = (c < 10) ? accv / (accp + 1e-16f) + b2[c] : -1e30f;
    float m = z;
    m = fmaxf(m, __shfl_xor(m, 1));
    m = fmaxf(m, __shfl_xor(m, 2));
    m = fmaxf(m, __shfl_xor(m, 4));
    m = fmaxf(m, __shfl_xor(m, 8));
    float p = (c < 10) ? expf(z - m) : 0.f;
    p += __shfl_xor(p, 1);
    p += __shfl_xor(p, 2);
    p += __shfl_xor(p, 4);
    p += __shfl_xor(p, 8);
    float lse = m + logf(p);
    if (sub == 0 && c < 10)
        out[(size_t)wid * 10 + c] = z - lse;
}

// ---------------------------------------------------------------------------
extern "C" void kernel_launch(void* const* d_in, const int* in_sizes, int n_in,
                              void* d_out, int out_size, void* d_ws, size_t ws_size,
                              hipStream_t stream)
{
    const float* x     = (const float*)d_in[0];
    const float* W1    = (const float*)d_in[1];
    const float* asrc1 = (const float*)d_in[2];
    const float* adst1 = (const float*)d_in[3];
    const float* b1    = (const float*)d_in[4];
    const float* W2    = (const float*)d_in[5];
    const float* asrc2 = (const float*)d_in[6];
    const float* adst2 = (const float*)d_in[7];
    const float* b2    = (const float*)d_in[8];
    const int*   ei    = (const int*)d_in[9];
    float* out = (float*)d_out;

    int F  = in_sizes[1] / 64;       // 512
    int Nn = in_sizes[0] / F;        // 100000
    int E  = in_sizes[9] / 2;        // 1600000
    int Ep = E + Nn;
    int nb = (Nn + 1023) / 1024;

    float* f = (float*)d_ws;
    __bf16* w1b = (__bf16*)f;  f += 512 * 64 / 2;   // 64KB, 16B-aligned
    float* h1   = f;  f += (size_t)Nn * 64;
    float* as1  = f;  f += (size_t)Nn * 8;
    float* ad1  = f;  f += (size_t)Nn * 8;
    float* h2   = f;  f += (size_t)Nn * 16;
    float* as2  = f;  f += Nn;
    float* ad2  = f;  f += Nn;
    int* ip = (int*)f;
    int* deg    = ip;  ip += Nn;
    int* rowptr = ip;  ip += Nn + 1;
    int* bsum   = ip;  ip += 256;
    int* rank   = ip;  ip += Ep;
    int* csr    = ip;  ip += Ep;

    int nbG = (Nn + 63) / 64;        // gemm blocks
    int nbS = (Ep + 255) / 256;      // scatter blocks

    // CSR histogram + W1 swizzle (fused, independent)
    hipMemsetAsync(deg, 0, (size_t)Nn * sizeof(int), stream);
    histw1_k<<<16 + nbS, 256, 0, stream>>>(ei, E, Nn, deg, rank, W1, w1b);

    // rowptr scan
    scan_a_k<<<nb, 256, 0, stream>>>(deg, Nn, bsum);
    scan_b_k<<<1, 256, 0, stream>>>(bsum, nb);
    scan_c_k<<<nb, 256, 0, stream>>>(deg, Nn, bsum, rowptr);

    // Overlapped: layer-1 GEMM (+attn dots) || atomic-free CSR scatter
    scatgemm_k<<<nbG + nbS, 256, 0, stream>>>(x, w1b, asrc1, adst1, h1, as1, ad1,
                                              ei, E, rowptr, rank, csr, Nn, nbG);

    // Layer-1 aggregate + fused node2 (bias/ELU/GEMM2/attn2 dots)
    agg1n_k<<<(Nn + 3) / 4, 256, 0, stream>>>(csr, rowptr, as1, ad1, h1,
                                              b1, W2, asrc2, adst2, h2, as2, ad2, Nn);

    // Layer-2 aggregate + fused bias + log_softmax
    agg2l_k<<<(Nn + 3) / 4, 256, 0, stream>>>(csr, rowptr, as2, ad2, h2, b2, out, Nn);
}

// Round 4
// 570.411 us; speedup vs baseline: 1.1750x; 1.0143x over previous
//
#include <hip/hip_runtime.h>
#include <math.h>

#define NEG 0.2f

typedef __bf16 bf16x8 __attribute__((ext_vector_type(8)));
typedef __bf16 bf16x4 __attribute__((ext_vector_type(4)));
typedef float  f32x4  __attribute__((ext_vector_type(4)));

// ---------------------------------------------------------------------------
// Fused: W1 pre-swizzle (blocks 0..15) + histogram+rank (remaining blocks).
// W1b slot i = (ch*4+lk)*64 + n holds 8 bf16: W1[ch*32+lk*8+j][n], j=0..7.
// ---------------------------------------------------------------------------
__global__ void histw1_k(const int* __restrict__ ei, int E, int Nn,
                         int* __restrict__ deg, int* __restrict__ rank,
                         const float* __restrict__ W1, __bf16* __restrict__ W1b)
{
    if (blockIdx.x < 16) {
        int i = blockIdx.x * 256 + threadIdx.x;   // 0..4095
        int n = i & 63;
        int k0 = (i >> 6) * 8;                    // (ch*4+lk)*8 == ch*32+lk*8
#pragma unroll
        for (int j = 0; j < 8; ++j)
            W1b[(size_t)i * 8 + j] = (__bf16)W1[(size_t)(k0 + j) * 64 + n];
        return;
    }
    int e = (blockIdx.x - 16) * 256 + threadIdx.x;
    int Ep = E + Nn;
    if (e >= Ep) return;
    int d = (e < E) ? ei[E + e] : e - E;
    rank[e] = atomicAdd(&deg[d], 1);
}

__global__ void scan_a_k(const int* __restrict__ deg, int Nn, int* __restrict__ bsum)
{
    __shared__ int tmp[256];
    int t = threadIdx.x;
    int base = blockIdx.x * 1024 + t * 4;
    int s = 0;
#pragma unroll
    for (int j = 0; j < 4; ++j) { int i = base + j; if (i < Nn) s += deg[i]; }
    tmp[t] = s;
    __syncthreads();
    for (int off = 1; off < 256; off <<= 1) {
        int a = (t >= off) ? tmp[t - off] : 0;
        __syncthreads();
        tmp[t] += a;
        __syncthreads();
    }
    if (t == 255) bsum[blockIdx.x] = tmp[255];
}

__global__ void scan_b_k(int* __restrict__ bsum, int nb)
{
    __shared__ int tmp[256];
    int t = threadIdx.x;
    int v = (t < nb) ? bsum[t] : 0;
    tmp[t] = v;
    __syncthreads();
    for (int off = 1; off < 256; off <<= 1) {
        int a = (t >= off) ? tmp[t - off] : 0;
        __syncthreads();
        tmp[t] += a;
        __syncthreads();
    }
    if (t < nb) bsum[t] = tmp[t] - v;  // exclusive
}

__global__ void scan_c_k(const int* __restrict__ deg, int Nn, const int* __restrict__ boff,
                         int* __restrict__ rowptr)
{
    __shared__ int tmp[256];
    int t = threadIdx.x;
    int base = blockIdx.x * 1024 + t * 4;
    int v[4];
    int s = 0;
#pragma unroll
    for (int j = 0; j < 4; ++j) {
        int i = base + j;
        v[j] = (i < Nn) ? deg[i] : 0;
        s += v[j];
    }
    tmp[t] = s;
    __syncthreads();
    for (int off = 1; off < 256; off <<= 1) {
        int a = (t >= off) ? tmp[t - off] : 0;
        __syncthreads();
        tmp[t] += a;
        __syncthreads();
    }
    int excl = boff[blockIdx.x] + tmp[t] - s;
#pragma unroll
    for (int j = 0; j < 4; ++j) {
        int i = base + j;
        if (i < Nn) {
            rowptr[i] = excl;
            excl += v[j];
            if (i == Nn - 1) rowptr[Nn] = excl;
        }
    }
}

// ---------------------------------------------------------------------------
// Fused: gemm1 (+attention dots) on blocks [0,nbG) + atomic-free CSR scatter
// on blocks [nbG,..). h1 now stored as bf16 (value path only; attention dots
// computed from f32 accumulators) -> halves agg1's gather stream and the
// epilogue write.
// GEMM: h1[N,64] = x[N,512] @ W1[512,64] via bf16 MFMA (16x16x32).
// C/D: col = lane&15, row = (lane>>4)*4 + reg (verified m89).
// ---------------------------------------------------------------------------
__global__ __launch_bounds__(256, 4) void scatgemm_k(
    const float* __restrict__ x, const __bf16* __restrict__ W1b,
    const float* __restrict__ asrc, const float* __restrict__ adst,
    __bf16* __restrict__ h1b, float* __restrict__ as1, float* __restrict__ ad1,
    const int* __restrict__ ei, int E,
    const int* __restrict__ rowptr, const int* __restrict__ rank,
    int* __restrict__ csr, int Nn, int nbG)
{
    if ((int)blockIdx.x >= nbG) {
        // ---- scatter path ----
        int e = ((int)blockIdx.x - nbG) * 256 + threadIdx.x;
        int Ep = E + Nn;
        if (e >= Ep) return;
        int s, d;
        if (e < E) { s = ei[e]; d = ei[E + e]; } else { s = d = e - E; }
        csr[rowptr[d] + rank[e]] = s;
        return;
    }
    // ---- gemm path ----
    int t = threadIdx.x;
    int wave = t >> 6, lane = t & 63;
    int lm = lane & 15, lk = lane >> 4;
    int rowa = blockIdx.x * 64 + wave * 16 + lm;          // A: m = lane&15
    const float* xrow = x + (size_t)(rowa < Nn ? rowa : 0) * 512;
    f32x4 acc[4] = {};
#pragma unroll
    for (int ch = 0; ch < 16; ++ch) {
        float4 a0 = *(const float4*)(xrow + ch * 32 + lk * 8);
        float4 a1 = *(const float4*)(xrow + ch * 32 + lk * 8 + 4);
        bf16x8 af;
        af[0] = (__bf16)a0.x; af[1] = (__bf16)a0.y;
        af[2] = (__bf16)a0.z; af[3] = (__bf16)a0.w;
        af[4] = (__bf16)a1.x; af[5] = (__bf16)a1.y;
        af[6] = (__bf16)a1.z; af[7] = (__bf16)a1.w;
#pragma unroll
        for (int nt = 0; nt < 4; ++nt) {
            bf16x8 bf = *(const bf16x8*)(W1b + ((size_t)((ch * 4 + lk) * 64) + nt * 16 + lm) * 8);
            acc[nt] = __builtin_amdgcn_mfma_f32_16x16x32_bf16(af, bf, acc[nt], 0, 0, 0);
        }
    }
    int rowbase = blockIdx.x * 64 + wave * 16 + lk * 4;
    // h1 store (bf16)
#pragma unroll
    for (int nt = 0; nt < 4; ++nt) {
#pragma unroll
        for (int j = 0; j < 4; ++j) {
            int gr = rowbase + j;
            if (gr < Nn) h1b[(size_t)gr * 64 + nt * 16 + lm] = (__bf16)acc[nt][j];
        }
    }
    // fused attention dots (f32 path): alpha_src[n,h] = sum_c h[n,h*8+c]*asrc[h*8+c]
#pragma unroll
    for (int nt = 0; nt < 4; ++nt) {
        float ws = asrc[nt * 16 + lm];
        float wd = adst[nt * 16 + lm];
#pragma unroll
        for (int j = 0; j < 4; ++j) {
            float sv = acc[nt][j] * ws;
            float dv = acc[nt][j] * wd;
            sv += __shfl_xor(sv, 1); dv += __shfl_xor(dv, 1);
            sv += __shfl_xor(sv, 2); dv += __shfl_xor(dv, 2);
            sv += __shfl_xor(sv, 4); dv += __shfl_xor(dv, 4);
            int gr = rowbase + j;
            if ((lm & 7) == 0 && gr < Nn) {
                int hh = nt * 2 + (lm >> 3);
                as1[(size_t)gr * 8 + hh] = sv;
                ad1[(size_t)gr * 8 + hh] = dv;
            }
        }
    }
}

// ---------------------------------------------------------------------------
// Layer-1 fused softmax+aggregate + node2 (bias+ELU+GEMM2(64x10)+layer-2
// attention dots): one wave per dst node. h1 gathered as bf16 (8B/lane/edge
// instead of 16B) -> gather stream halved to ~218MB logical, table 12.8MB.
// ---------------------------------------------------------------------------
__global__ __launch_bounds__(256, 4) void agg1n_k(const int* __restrict__ csr,
                                                  const int* __restrict__ rowptr,
                                                  const float* __restrict__ as1,
                                                  const float* __restrict__ ad1,
                                                  const __bf16* __restrict__ h1b,
                                                  const float* __restrict__ b1,
                                                  const float* __restrict__ W2,
                                                  const float* __restrict__ as2w,
                                                  const float* __restrict__ ad2w,
                                                  float* __restrict__ h2,
                                                  float* __restrict__ as2,
                                                  float* __restrict__ ad2, int Nn)
{
    __shared__ float W2s[640];
    for (int i = threadIdx.x; i < 640; i += 256) W2s[i] = W2[i];
    __syncthreads();   // before any early exit (divergent-barrier safety)

    int wid = (blockIdx.x * 256 + threadIdx.x) >> 6;
    if (wid >= Nn) return;
    int lane = threadIdx.x & 63;
    int sub = lane >> 4;
    int c4 = lane & 15;
    int h = c4 >> 1;
    float adv = ad1[wid * 8 + h];
    int start = rowptr[wid];
    int len = rowptr[wid + 1] - start;
    float accp = 0.f;
    float4 accv = make_float4(0.f, 0.f, 0.f, 0.f);
    int i = sub;
    for (; i + 12 < len; i += 16) {
        int s0 = csr[start + i];
        int s1 = csr[start + i + 4];
        int s2 = csr[start + i + 8];
        int s3 = csr[start + i + 12];
        float e0 = as1[s0 * 8 + h] + adv;
        float e1 = as1[s1 * 8 + h] + adv;
        float e2 = as1[s2 * 8 + h] + adv;
        float e3 = as1[s3 * 8 + h] + adv;
        bf16x4 hv0 = *(const bf16x4*)(h1b + (size_t)s0 * 64 + c4 * 4);
        bf16x4 hv1 = *(const bf16x4*)(h1b + (size_t)s1 * 64 + c4 * 4);
        bf16x4 hv2 = *(const bf16x4*)(h1b + (size_t)s2 * 64 + c4 * 4);
        bf16x4 hv3 = *(const bf16x4*)(h1b + (size_t)s3 * 64 + c4 * 4);
        e0 = e0 > 0.f ? e0 : NEG * e0;
        e1 = e1 > 0.f ? e1 : NEG * e1;
        e2 = e2 > 0.f ? e2 : NEG * e2;
        e3 = e3 > 0.f ? e3 : NEG * e3;
        float p0 = __expf(e0), p1 = __expf(e1), p2 = __expf(e2), p3 = __expf(e3);
        accp += (p0 + p1) + (p2 + p3);
        accv.x += p0 * (float)hv0[0] + p1 * (float)hv1[0] + p2 * (float)hv2[0] + p3 * (float)hv3[0];
        accv.y += p0 * (float)hv0[1] + p1 * (float)hv1[1] + p2 * (float)hv2[1] + p3 * (float)hv3[1];
        accv.z += p0 * (float)hv0[2] + p1 * (float)hv1[2] + p2 * (float)hv2[2] + p3 * (float)hv3[2];
        accv.w += p0 * (float)hv0[3] + p1 * (float)hv1[3] + p2 * (float)hv2[3] + p3 * (float)hv3[3];
    }
    for (; i < len; i += 4) {
        int s0 = csr[start + i];
        float e0 = as1[s0 * 8 + h] + adv;
        bf16x4 hv0 = *(const bf16x4*)(h1b + (size_t)s0 * 64 + c4 * 4);
        e0 = e0 > 0.f ? e0 : NEG * e0;
        float p0 = __expf(e0);
        accp += p0;
        accv.x += p0 * (float)hv0[0];
        accv.y += p0 * (float)hv0[1];
        accv.z += p0 * (float)hv0[2];
        accv.w += p0 * (float)hv0[3];
    }
    accp   += __shfl_xor(accp, 16);
    accv.x += __shfl_xor(accv.x, 16);
    accv.y += __shfl_xor(accv.y, 16);
    accv.z += __shfl_xor(accv.z, 16);
    accv.w += __shfl_xor(accv.w, 16);
    accp   += __shfl_xor(accp, 32);
    accv.x += __shfl_xor(accv.x, 32);
    accv.y += __shfl_xor(accv.y, 32);
    accv.z += __shfl_xor(accv.z, 32);
    accv.w += __shfl_xor(accv.w, 32);

    // ---- fused node2: bias + ELU + 64x10 matvec + layer-2 attn dots ----
    float inv = 1.f / (accp + 1e-16f);
    float4 b = *(const float4*)(b1 + c4 * 4);
    float g0 = accv.x * inv + b.x; g0 = g0 > 0.f ? g0 : expm1f(g0);
    float g1 = accv.y * inv + b.y; g1 = g1 > 0.f ? g1 : expm1f(g1);
    float g2 = accv.z * inv + b.z; g2 = g2 > 0.f ? g2 : expm1f(g2);
    float g3 = accv.w * inv + b.w; g3 = g3 > 0.f ? g3 : expm1f(g3);
    int k0 = c4 * 4;
    float aj[10];
#pragma unroll
    for (int j = 0; j < 10; ++j)
        aj[j] = g0 * W2s[(k0 + 0) * 10 + j] + g1 * W2s[(k0 + 1) * 10 + j]
              + g2 * W2s[(k0 + 2) * 10 + j] + g3 * W2s[(k0 + 3) * 10 + j];
#pragma unroll
    for (int m = 1; m <= 8; m <<= 1) {
#pragma unroll
        for (int j = 0; j < 10; ++j) aj[j] += __shfl_xor(aj[j], m);
    }
    if (lane == 0) {
        float s2 = 0.f, d2 = 0.f;
#pragma unroll
        for (int j = 0; j < 10; ++j) { s2 += aj[j] * as2w[j]; d2 += aj[j] * ad2w[j]; }
        *(float4*)(h2 + (size_t)wid * 16 + 0) = make_float4(aj[0], aj[1], aj[2], aj[3]);
        *(float4*)(h2 + (size_t)wid * 16 + 4) = make_float4(aj[4], aj[5], aj[6], aj[7]);
        h2[(size_t)wid * 16 + 8] = aj[8];
        h2[(size_t)wid * 16 + 9] = aj[9];
        as2[wid] = s2;
        ad2[wid] = d2;
    }
}

// ---------------------------------------------------------------------------
// Layer-2 fused softmax+aggregate + bias + log_softmax: one wave per dst.
// ---------------------------------------------------------------------------
__global__ __launch_bounds__(256) void agg2l_k(const int* __restrict__ csr,
                                               const int* __restrict__ rowptr,
                                               const float* __restrict__ as2,
                                               const float* __restrict__ ad2,
                                               const float* __restrict__ h2,
                                               const float* __restrict__ b2,
                                               float* __restrict__ out, int Nn)
{
    int wid = (blockIdx.x * 256 + threadIdx.x) >> 6;
    if (wid >= Nn) return;
    int lane = threadIdx.x & 63;
    int sub = lane >> 4;
    int c = lane & 15;
    float adv = ad2[wid];
    int start = rowptr[wid];
    int len = rowptr[wid + 1] - start;
    float accp = 0.f, accv = 0.f;
    int i = sub;
    for (; i + 12 < len; i += 16) {
        int s0 = csr[start + i];
        int s1 = csr[start + i + 4];
        int s2 = csr[start + i + 8];
        int s3 = csr[start + i + 12];
        float e0 = as2[s0] + adv;
        float e1 = as2[s1] + adv;
        float e2 = as2[s2] + adv;
        float e3 = as2[s3] + adv;
        float v0 = (c < 10) ? h2[(size_t)s0 * 16 + c] : 0.f;
        float v1 = (c < 10) ? h2[(size_t)s1 * 16 + c] : 0.f;
        float v2 = (c < 10) ? h2[(size_t)s2 * 16 + c] : 0.f;
        float v3 = (c < 10) ? h2[(size_t)s3 * 16 + c] : 0.f;
        e0 = e0 > 0.f ? e0 : NEG * e0;
        e1 = e1 > 0.f ? e1 : NEG * e1;
        e2 = e2 > 0.f ? e2 : NEG * e2;
        e3 = e3 > 0.f ? e3 : NEG * e3;
        float p0 = __expf(e0), p1 = __expf(e1), p2 = __expf(e2), p3 = __expf(e3);
        accp += (p0 + p1) + (p2 + p3);
        accv += p0 * v0 + p1 * v1 + p2 * v2 + p3 * v3;
    }
    for (; i < len; i += 4) {
        int s0 = csr[start + i];
        float e0 = as2[s0] + adv;
        float v0 = (c < 10) ? h2[(size_t)s0 * 16 + c] : 0.f;
        e0 = e0 > 0.f ? e0 : NEG * e0;
        float p0 = __expf(e0);
        accp += p0;
        accv += p0 * v0;
    }
    accp += __shfl_xor(accp, 16);
    accv += __shfl_xor(accv, 16);
    accp += __shfl_xor(accp, 32);
    accv += __shfl_xor(accv, 32);

    // ---- fused bias + log_softmax over the 10 classes ----
    float z = (c < 10) ? accv / (accp + 1e-16f) + b2[c] : -1e30f;
    float m = z;
    m = fmaxf(m, __shfl_xor(m, 1));
    m = fmaxf(m, __shfl_xor(m, 2));
    m = fmaxf(m, __shfl_xor(m, 4));
    m = fmaxf(m, __shfl_xor(m, 8));
    float p = (c < 10) ? expf(z - m) : 0.f;
    p += __shfl_xor(p, 1);
    p += __shfl_xor(p, 2);
    p += __shfl_xor(p, 4);
    p += __shfl_xor(p, 8);
    float lse = m + logf(p);
    if (sub == 0 && c < 10)
        out[(size_t)wid * 10 + c] = z - lse;
}

// ---------------------------------------------------------------------------
extern "C" void kernel_launch(void* const* d_in, const int* in_sizes, int n_in,
                              void* d_out, int out_size, void* d_ws, size_t ws_size,
                              hipStream_t stream)
{
    const float* x     = (const float*)d_in[0];
    const float* W1    = (const float*)d_in[1];
    const float* asrc1 = (const float*)d_in[2];
    const float* adst1 = (const float*)d_in[3];
    const float* b1    = (const float*)d_in[4];
    const float* W2    = (const float*)d_in[5];
    const float* asrc2 = (const float*)d_in[6];
    const float* adst2 = (const float*)d_in[7];
    const float* b2    = (const float*)d_in[8];
    const int*   ei    = (const int*)d_in[9];
    float* out = (float*)d_out;

    int F  = in_sizes[1] / 64;       // 512
    int Nn = in_sizes[0] / F;        // 100000
    int E  = in_sizes[9] / 2;        // 1600000
    int Ep = E + Nn;
    int nb = (Nn + 1023) / 1024;

    float* f = (float*)d_ws;
    __bf16* w1b = (__bf16*)f;  f += 512 * 64 / 2;      // 64KB, 16B-aligned
    __bf16* h1b = (__bf16*)f;  f += (size_t)Nn * 32;   // Nn*64 bf16
    float* as1  = f;  f += (size_t)Nn * 8;
    float* ad1  = f;  f += (size_t)Nn * 8;
    float* h2   = f;  f += (size_t)Nn * 16;
    float* as2  = f;  f += Nn;
    float* ad2  = f;  f += Nn;
    int* ip = (int*)f;
    int* deg    = ip;  ip += Nn;
    int* rowptr = ip;  ip += Nn + 1;
    int* bsum   = ip;  ip += 256;
    int* rank   = ip;  ip += Ep;
    int* csr    = ip;  ip += Ep;

    int nbG = (Nn + 63) / 64;        // gemm blocks
    int nbS = (Ep + 255) / 256;      // scatter blocks

    // CSR histogram + W1 swizzle (fused, independent)
    hipMemsetAsync(deg, 0, (size_t)Nn * sizeof(int), stream);
    histw1_k<<<16 + nbS, 256, 0, stream>>>(ei, E, Nn, deg, rank, W1, w1b);

    // rowptr scan
    scan_a_k<<<nb, 256, 0, stream>>>(deg, Nn, bsum);
    scan_b_k<<<1, 256, 0, stream>>>(bsum, nb);
    scan_c_k<<<nb, 256, 0, stream>>>(deg, Nn, bsum, rowptr);

    // Layer-1 GEMM (+attn dots, bf16 h1 store) || atomic-free CSR scatter
    scatgemm_k<<<nbG + nbS, 256, 0, stream>>>(x, w1b, asrc1, adst1, h1b, as1, ad1,
                                              ei, E, rowptr, rank, csr, Nn, nbG);

    // Layer-1 aggregate + fused node2 (bias/ELU/GEMM2/attn2 dots)
    agg1n_k<<<(Nn + 3) / 4, 256, 0, stream>>>(csr, rowptr, as1, ad1, h1b,
                                              b1, W2, asrc2, adst2, h2, as2, ad2, Nn);

    // Layer-2 aggregate + fused bias + log_softmax
    agg2l_k<<<(Nn + 3) / 4, 256, 0, stream>>>(csr, rowptr, as2, ad2, h2, b2, out, Nn);
}